// Round 2
// baseline (100.465 us; speedup 1.0000x reference)
//
#include <hip/hip_runtime.h>
#include <math.h>

#define OUT_H 7
#define OUT_W 7
#define N_C 256
#define FH 38
#define FW 38
#define NUM_ROIS 256
#define SPATIAL_SCALE 0.0625f

// One WAVE per (roi, channel). Lane L owns column x1+L of the ROI region
// (rw <= 38 <= 64, so one row fits in one wave-load -> 1-2 cachelines,
// fully coalesced, and all loop bounds are wave-uniform: zero divergence
// in the hot loop). Per-lane column maxima per output-row bucket go to a
// 64-float LDS strip; lanes 0..48 then reduce their (i,j) column window
// (<=6 scalar LDS reads) and store 49 consecutive floats (coalesced).
__global__ __launch_bounds__(256) void roi_pool_wave(
    const float* __restrict__ feat,
    const float* __restrict__ rois,
    float* __restrict__ out)
{
    __shared__ float cmax[4][OUT_H][64];   // per-wave strips: 7 KB/block

    const int lane = threadIdx.x & 63;
    const int wv   = threadIdx.x >> 6;
    const int g    = blockIdx.x * 4 + wv;  // global wave id = r*256 + c
    const int r    = g >> 8;
    const int c    = g & 255;

    const float* roi = rois + r * 5;
    const int b  = (int)roi[0];
    const int x1 = (int)(roi[1] * SPATIAL_SCALE);  // floor, inputs >= 0
    const int y1 = (int)(roi[2] * SPATIAL_SCALE);
    const int x2 = (int)(roi[3] * SPATIAL_SCALE);
    const int y2 = (int)(roi[4] * SPATIAL_SCALE);
    const int rh = y2 - y1 + 1;
    const int rw = x2 - x1 + 1;

    const float* plane   = feat + ((size_t)(b * N_C + c)) * (FH * FW);
    const float* colbase = plane + x1 + lane;
    const bool   active  = lane < rw;      // guard: x1+lane may run off buffer

    #pragma unroll
    for (int i = 0; i < OUT_H; ++i) {
        const int hs = y1 + (i * rh) / OUT_H;                 // floor-div, >=0
        const int he = y1 + ((i + 1) * rh + OUT_H - 1) / OUT_H;
        float m = -INFINITY;
        if (active) {
            for (int h = hs; h < he; ++h)                      // wave-uniform bounds
                m = fmaxf(m, colbase[h * FW]);
        }
        cmax[wv][i][lane] = m;
    }
    __syncthreads();

    if (lane < OUT_H * OUT_W) {
        const int i = lane / OUT_W;
        const int j = lane % OUT_W;
        const int ws = (j * rw) / OUT_W;                       // relative to x1
        const int we = ((j + 1) * rw + OUT_W - 1) / OUT_W;     // <= rw
        float o = -INFINITY;
        for (int t = ws; t < we; ++t)
            o = fmaxf(o, cmax[wv][i][t]);
        out[((size_t)(r * N_C + c)) * (OUT_H * OUT_W) + lane] = o;
    }
}

extern "C" void kernel_launch(void* const* d_in, const int* in_sizes, int n_in,
                              void* d_out, int out_size, void* d_ws, size_t ws_size,
                              hipStream_t stream) {
    const float* feat = (const float*)d_in[0];
    const float* rois = (const float*)d_in[1];
    float* out = (float*)d_out;

    // 256 rois * 256 channels = 65536 waves; 4 waves (256 threads) per block
    const int grid = (NUM_ROIS * N_C) / 4;   // 16384 blocks
    roi_pool_wave<<<grid, 256, 0, stream>>>(feat, rois, out);
}

// Round 3
// 84.301 us; speedup vs baseline: 1.1917x; 1.1917x over previous
//
#include <hip/hip_runtime.h>
#include <math.h>

#define OUT_H 7
#define OUT_W 7
#define N_C 256
#define N_IMG 2
#define FH 38
#define FW 38
#define PLANE (FH * FW)        // 1444 floats = 5776 B (= 361 float4)
#define NUM_ROIS 256
#define ROIS_PER_BLK 32
#define SPATIAL_SCALE 0.0625f

// Block = (channel, chunk of 32 rois). Both images' channel-c planes are
// staged in LDS once (11.5 KB) and reused by 32 rois * 49 outputs = 1568
// outputs -> the hot loop does ZERO global loads (fixes the R1/R2 global
// latency bound). 2048 blocks = 8 blocks/CU (32 waves/CU, LDS 93/160 KB).
// Each thread computes ~6 independent window-maxes from LDS; consecutive
// threads share a roi (49 lanes/roi) so window bounds are near-uniform
// within a wave. Stores: 196 B contiguous per (r,c) group, nontemporal.
__global__ __launch_bounds__(256) void roi_pool_lds(
    const float* __restrict__ feat,
    const float* __restrict__ rois,
    float* __restrict__ out)
{
    __shared__ float s_plane[N_IMG][PLANE];                  // 11552 B
    __shared__ int s_x1[ROIS_PER_BLK], s_y1[ROIS_PER_BLK];
    __shared__ int s_rw[ROIS_PER_BLK], s_rh[ROIS_PER_BLK];
    __shared__ int s_b [ROIS_PER_BLK];

    const int tid   = threadIdx.x;
    const int c     = blockIdx.x >> 3;    // 0..255
    const int chunk = blockIdx.x & 7;     // 0..7
    const int r0    = chunk * ROIS_PER_BLK;

    // Stage channel-c plane of both images, float4-vectorized (361 each).
    const float4* f0 = (const float4*)(feat + (size_t)c * PLANE);
    const float4* f1 = (const float4*)(feat + (size_t)(N_C + c) * PLANE);
    float4* s0 = (float4*)s_plane[0];
    float4* s1 = (float4*)s_plane[1];
    for (int p = tid; p < PLANE / 4; p += 256) {
        s0[p] = f0[p];
        s1[p] = f1[p];
    }

    // Decode this chunk's 32 rois.
    if (tid < ROIS_PER_BLK) {
        const float* roi = rois + (size_t)(r0 + tid) * 5;
        const int b  = (int)roi[0];
        const int x1 = (int)(roi[1] * SPATIAL_SCALE);  // floor, inputs >= 0
        const int y1 = (int)(roi[2] * SPATIAL_SCALE);
        const int x2 = (int)(roi[3] * SPATIAL_SCALE);
        const int y2 = (int)(roi[4] * SPATIAL_SCALE);
        s_b [tid] = b;
        s_x1[tid] = x1;
        s_y1[tid] = y1;
        s_rw[tid] = x2 - x1 + 1;
        s_rh[tid] = y2 - y1 + 1;
    }
    __syncthreads();

    // 1568 outputs per block, ~6 per thread, all windows read from LDS.
    for (int id = tid; id < ROIS_PER_BLK * (OUT_H * OUT_W); id += 256) {
        const int rl = id / 49;
        const int ij = id - rl * 49;
        const int i  = ij / OUT_W;
        const int j  = ij - i * OUT_W;

        const int rh = s_rh[rl], rw = s_rw[rl];
        const int hs = s_y1[rl] + (i * rh) / OUT_H;                 // floor-div
        const int he = s_y1[rl] + ((i + 1) * rh + OUT_H - 1) / OUT_H;
        const int ws = s_x1[rl] + (j * rw) / OUT_W;
        const int we = s_x1[rl] + ((j + 1) * rw + OUT_W - 1) / OUT_W;

        const float* pl = s_plane[s_b[rl]];
        float m = -INFINITY;
        for (int h = hs; h < he; ++h) {
            const float* row = pl + h * FW;
            for (int w = ws; w < we; ++w)
                m = fmaxf(m, row[w]);
        }
        __builtin_nontemporal_store(
            m, out + ((size_t)(r0 + rl) * N_C + c) * (OUT_H * OUT_W) + ij);
    }
}

extern "C" void kernel_launch(void* const* d_in, const int* in_sizes, int n_in,
                              void* d_out, int out_size, void* d_ws, size_t ws_size,
                              hipStream_t stream) {
    const float* feat = (const float*)d_in[0];
    const float* rois = (const float*)d_in[1];
    float* out = (float*)d_out;

    const int grid = N_C * (NUM_ROIS / ROIS_PER_BLK);  // 256 * 8 = 2048
    roi_pool_lds<<<grid, 256, 0, stream>>>(feat, rois, out);
}